// Round 7
// baseline (95.685 us; speedup 1.0000x reference)
//
#include <hip/hip_runtime.h>

// Chamfer distance, B=16, N=M=4096, D=3, fp32. memset + single kernel.
// d(i,j) = n_q + (n_t - 2 q.t).
// Each block stages 2048 targets (one half of the cloud) into LDS, SoA
// pair-group format: group g = targets (2g,2g+1) split into
// tA[g]=[x0,x1,y0,y1], tB[g]=[z0,z1,w0,w1] (w=|t|^2). Inner loop:
// wave-uniform ds_read_b128 broadcast + 3 v_pk_fma_f32 + 1 v_min3_f32
// per (2 targets x query), QPL=4 queries/lane. The two target-halves are
// combined across blocks with uint atomicMin (valid for clamped
// non-negative fp32), d_out pre-set to 0x7F7F7F7F via hipMemsetAsync.
// LDS 40 KB -> 4 blocks/CU; __launch_bounds__(512,8) -> 8 waves/SIMD.

#define CB 16
#define CN 4096
#define CM 4096
#define QPL 4            // queries per lane
#define WVS 8            // waves per block (512 threads)
#define QPB (64 * QPL)   // queries per block = 256
#define HALF_T 2048      // targets staged per block
#define GRP_H  (HALF_T / 2)     // 1024 groups
#define GRP_PW (GRP_H / WVS)    // 128 groups per wave

typedef float v4f __attribute__((ext_vector_type(4)));
typedef float v2f __attribute__((ext_vector_type(2)));

// One pair-group (2 targets) vs one query: 3 pk_fma + 1 min3, no movs.
__device__ __forceinline__ void grp(const v4f t0, const v4f t1,
                                    const v2f mx, const v2f my, const v2f mz,
                                    float& best)
{
    v2f d;
    asm("v_pk_fma_f32 %0, %1, %2, %3" : "=&v"(d) : "v"(mz), "v"(t1.xy), "v"(t1.zw));
    asm("v_pk_fma_f32 %0, %1, %2, %0" : "+v"(d) : "v"(my), "v"(t0.zw));
    asm("v_pk_fma_f32 %0, %1, %2, %0" : "+v"(d) : "v"(mx), "v"(t0.xy));
    asm("v_min3_f32 %0, %1, %2, %0" : "+v"(best) : "v"(d.x), "v"(d.y));
}

// grid: (32 = 16 qtiles * 2 target-halves, B, 2 dirs) = 1024 blocks.
__global__ __launch_bounds__(512, 8) void chamfer_min(
    const float* __restrict__ x1, const float* __restrict__ x2,
    float* __restrict__ out)
{
    const int dir   = blockIdx.z;
    const int b     = blockIdx.y;
    const int qtile = blockIdx.x >> 1;
    const int thalf = blockIdx.x & 1;

    const float* __restrict__ qraw = (dir ? x2 : x1) + (size_t)b * CN * 3;
    const float* __restrict__ traw = (dir ? x1 : x2) + (size_t)b * CM * 3;
    float* __restrict__ o = out + (dir ? ((size_t)CB * CN + (size_t)b * CM)
                                       : ((size_t)b * CN));

    __shared__ v4f tA[GRP_H];               // 16 KB: (x0,x1,y0,y1)
    __shared__ v4f tB[GRP_H];               // 16 KB: (z0,z1,w0,w1)
    __shared__ float red[WVS][QPL][64];     //  8 KB

    const int tid  = threadIdx.x;
    const int lane = tid & 63;
    const int wave = __builtin_amdgcn_readfirstlane(tid >> 6);

    // ---- Stage: thread t packs groups t and t+512. 16 B lane-stride
    // writes per store -> physically optimal LDS write pattern. ----
    #pragma unroll
    for (int p = 0; p < 2; ++p) {
        const int g = tid + p * 512;
        const float* r = traw + ((size_t)thalf * HALF_T + 2 * (size_t)g) * 3;
        v2f r01 = *(const v2f*)(r);        // x0,y0
        v2f r23 = *(const v2f*)(r + 2);    // z0,x1
        v2f r45 = *(const v2f*)(r + 4);    // y1,z1
        float w0 = fmaf(r01.x, r01.x, fmaf(r01.y, r01.y, r23.x * r23.x));
        float w1 = fmaf(r23.y, r23.y, fmaf(r45.x, r45.x, r45.y * r45.y));
        tA[g] = (v4f){r01.x, r23.y, r01.y, r45.x};
        tB[g] = (v4f){r23.x, r45.y, w0, w1};
    }

    // ---- Queries: 4 per lane, constants premultiplied by -2. ----
    v2f mx2[QPL], my2[QPL], mz2[QPL];
    #pragma unroll
    for (int k = 0; k < QPL; ++k) {
        int q = qtile * QPB + lane + 64 * k;
        float qx = qraw[3 * q + 0];
        float qy = qraw[3 * q + 1];
        float qz = qraw[3 * q + 2];
        mx2[k] = (v2f){-2.0f * qx, -2.0f * qx};
        my2[k] = (v2f){-2.0f * qy, -2.0f * qy};
        mz2[k] = (v2f){-2.0f * qz, -2.0f * qz};
    }

    float best[QPL];
    #pragma unroll
    for (int k = 0; k < QPL; ++k) best[k] = 1e30f;

    __syncthreads();

    // ---- Scan: wave w owns groups [w*128, (w+1)*128). ----
    const int gb = wave * GRP_PW;
    #pragma unroll 1
    for (int g = 0; g < GRP_PW; g += 2) {
        v4f a0 = tA[gb + g];
        v4f a1 = tB[gb + g];
        v4f b0 = tA[gb + g + 1];
        v4f b1 = tB[gb + g + 1];
        #pragma unroll
        for (int k = 0; k < QPL; ++k)
            grp(a0, a1, mx2[k], my2[k], mz2[k], best[k]);
        #pragma unroll
        for (int k = 0; k < QPL; ++k)
            grp(b0, b1, mx2[k], my2[k], mz2[k], best[k]);
    }

    // ---- Cross-wave combine; nq recomputed from consts (saves VGPRs). ----
    #pragma unroll
    for (int k = 0; k < QPL; ++k) {
        float nq = 0.25f * fmaf(mx2[k].x, mx2[k].x,
                          fmaf(my2[k].x, my2[k].x, mz2[k].x * mz2[k].x));
        red[wave][k][lane] = best[k] + nq;
    }
    __syncthreads();

    if (tid < QPB) {
        const int k = tid >> 6;
        const int l = tid & 63;
        float v = red[0][k][l];
        #pragma unroll
        for (int w = 1; w < WVS; ++w)
            v = fminf(v, red[w][k][l]);
        // Clamped non-negative fp32: uint compare == float compare.
        atomicMin((unsigned int*)(o + qtile * QPB + tid),
                  __float_as_uint(fmaxf(v, 0.0f)));
    }
}

extern "C" void kernel_launch(void* const* d_in, const int* in_sizes, int n_in,
                              void* d_out, int out_size, void* d_ws, size_t ws_size,
                              hipStream_t stream) {
    const float* x1 = (const float*)d_in[0];   // [B,N,3]
    const float* x2 = (const float*)d_in[1];   // [B,M,3]
    float* out = (float*)d_out;

    // Init to 0x7F7F7F7F (= 3.39e38): larger than any clamped distance,
    // so uint atomicMin always overwrites. Capture-safe memset node.
    hipMemsetAsync(out, 0x7F, (size_t)out_size * sizeof(float), stream);

    dim3 grid(32, CB, 2);
    chamfer_min<<<grid, 512, 0, stream>>>(x1, x2, out);
}